// Round 1
// baseline (2091.978 us; speedup 1.0000x reference)
//
#include <hip/hip_runtime.h>
#include <stdint.h>

#define B_  4
#define H_  16
#define N_  1024
#define D_  64
#define IB  16
#define JB  16
#define KV_HS 1032            // ushort stride per head block (16*64 + 8 pad)
#define SS_HS 272             // float stride per head block (16*17)
#define SS_IS 17

__device__ __forceinline__ ushort f2bf(float f) {
    uint32_t x = __float_as_uint(f);
    uint32_t r = (x + 0x7fffu + ((x >> 16) & 1u)) >> 16;
    return (ushort)r;
}
__device__ __forceinline__ float bflo(uint32_t u) { return __uint_as_float(u << 16); }
__device__ __forceinline__ float bfhi(uint32_t u) { return __uint_as_float(u & 0xffff0000u); }

__global__ __launch_bounds__(256, 1)
void attend_th_kernel(const float* __restrict__ q, const float* __restrict__ k,
                      const float* __restrict__ v, const float* __restrict__ Wpre,
                      const float* __restrict__ Wpost, float* __restrict__ out) {
    __shared__ ushort Ks[H_ * KV_HS];     // 33024 B
    __shared__ ushort Vs[H_ * KV_HS];     // 33024 B
    __shared__ float  Ss[H_ * SS_HS];     // 17408 B
    __shared__ float  Ps[H_ * SS_HS];     // 17408 B
    __shared__ float  Wpre_s[256];
    __shared__ float  Wpost_s[256];

    const int t  = threadIdx.x;
    const int b  = blockIdx.x >> 6;        // 64 i-tiles per batch
    const int it = blockIdx.x & 63;
    const int i0 = it * IB;
    const int a  = t >> 4;                 // head role (h for S/P, g for mix/out)
    const int ii = t & 15;
    const int i  = i0 + ii;

    Wpre_s[t]  = Wpre[t];
    Wpost_s[t] = Wpost[t];

    // q row (head a, row i) into registers, fp32
    float qr[D_];
    {
        const float4* qp = (const float4*)(q + (((size_t)b * H_ + a) * N_ + i) * D_);
        #pragma unroll
        for (int x = 0; x < 16; ++x) {
            float4 f = qp[x];
            qr[4*x+0] = f.x; qr[4*x+1] = f.y; qr[4*x+2] = f.z; qr[4*x+3] = f.w;
        }
    }

    const float scale = 0.125f;
    const int ntiles = it + 1;

    // ================= Phase A: softmax denominators =================
    float lacc = 0.0f;
    for (int jt = 0; jt < ntiles; ++jt) {
        const int j0 = jt * JB;
        __syncthreads();
        // load K tile: 16 heads x 16 rows x 64, fp32 -> bf16 LDS
        #pragma unroll
        for (int rep = 0; rep < 16; ++rep) {
            int f = rep * 256 + t;
            int e = f * 4;
            int h = e >> 10;
            int r = (e >> 6) & 15;
            int d = e & 63;
            const float4 kk = *(const float4*)(k + (((size_t)b*H_ + h)*N_ + j0 + r)*D_ + d);
            ushort* dst = &Ks[h*KV_HS + r*64 + d];
            *(ushort2*)(dst)     = make_ushort2(f2bf(kk.x), f2bf(kk.y));
            *(ushort2*)(dst + 2) = make_ushort2(f2bf(kk.z), f2bf(kk.w));
        }
        __syncthreads();
        // S[a][ii][jj] = scale * q(a,i) . k(a,j0+jj)
        {
            const uint32_t* kbase = (const uint32_t*)&Ks[a * KV_HS];
            #pragma unroll 4
            for (int jj = 0; jj < JB; ++jj) {
                const uint32_t* kp = kbase + jj * 32;
                float s0 = 0.f, s1 = 0.f;
                #pragma unroll
                for (int dd = 0; dd < 32; dd += 2) {
                    uint32_t u0 = kp[dd], u1 = kp[dd+1];
                    s0 += qr[2*dd+0] * bflo(u0) + qr[2*dd+1] * bfhi(u0);
                    s1 += qr[2*dd+2] * bflo(u1) + qr[2*dd+3] * bfhi(u1);
                }
                Ss[a*SS_HS + ii*SS_IS + jj] = (s0 + s1) * scale;
            }
        }
        __syncthreads();
        // pre-mix + exp accumulate (thread role a = softmax head g)
        {
            const int jmax = (jt == it) ? ii : (JB - 1);
            #pragma unroll 4
            for (int jj = 0; jj < JB; ++jj) {
                float m = 0.f;
                #pragma unroll
                for (int h = 0; h < 16; ++h)
                    m += Wpre_s[a*16 + h] * Ss[h*SS_HS + ii*SS_IS + jj];
                if (jj <= jmax) lacc += __expf(m);
            }
        }
    }
    const float lrecip = 1.0f / lacc;

    // ================= Phase B: output =================
    float O[D_];
    #pragma unroll
    for (int d = 0; d < D_; ++d) O[d] = 0.f;

    for (int jt = 0; jt < ntiles; ++jt) {
        const int j0 = jt * JB;
        __syncthreads();
        // load K and V tiles
        #pragma unroll
        for (int rep = 0; rep < 16; ++rep) {
            int f = rep * 256 + t;
            int e = f * 4;
            int h = e >> 10;
            int r = (e >> 6) & 15;
            int d = e & 63;
            size_t off = (((size_t)b*H_ + h)*N_ + j0 + r)*D_ + d;
            const float4 kk = *(const float4*)(k + off);
            const float4 vv = *(const float4*)(v + off);
            ushort* dk = &Ks[h*KV_HS + r*64 + d];
            *(ushort2*)(dk)     = make_ushort2(f2bf(kk.x), f2bf(kk.y));
            *(ushort2*)(dk + 2) = make_ushort2(f2bf(kk.z), f2bf(kk.w));
            ushort* dv = &Vs[h*KV_HS + r*64 + d];
            *(ushort2*)(dv)     = make_ushort2(f2bf(vv.x), f2bf(vv.y));
            *(ushort2*)(dv + 2) = make_ushort2(f2bf(vv.z), f2bf(vv.w));
        }
        __syncthreads();
        // S (recompute)
        {
            const uint32_t* kbase = (const uint32_t*)&Ks[a * KV_HS];
            #pragma unroll 4
            for (int jj = 0; jj < JB; ++jj) {
                const uint32_t* kp = kbase + jj * 32;
                float s0 = 0.f, s1 = 0.f;
                #pragma unroll
                for (int dd = 0; dd < 32; dd += 2) {
                    uint32_t u0 = kp[dd], u1 = kp[dd+1];
                    s0 += qr[2*dd+0] * bflo(u0) + qr[2*dd+1] * bfhi(u0);
                    s1 += qr[2*dd+2] * bflo(u1) + qr[2*dd+3] * bfhi(u1);
                }
                Ss[a*SS_HS + ii*SS_IS + jj] = (s0 + s1) * scale;
            }
        }
        __syncthreads();
        // P[a][ii][jj] = exp(pre-mix)/l  (thread role a = softmax head)
        {
            const int jmax = (jt == it) ? ii : (JB - 1);
            #pragma unroll 4
            for (int jj = 0; jj < JB; ++jj) {
                float m = 0.f;
                #pragma unroll
                for (int h = 0; h < 16; ++h)
                    m += Wpre_s[a*16 + h] * Ss[h*SS_HS + ii*SS_IS + jj];
                Ps[a*SS_HS + ii*SS_IS + jj] = (jj <= jmax) ? __expf(m) * lrecip : 0.f;
            }
        }
        __syncthreads();
        // post-mix + PV accumulate (thread role a = output head g)
        {
            const uint32_t* vbase = (const uint32_t*)&Vs[a * KV_HS];
            #pragma unroll 2
            for (int jj = 0; jj < JB; ++jj) {
                float w = 0.f;
                #pragma unroll
                for (int h = 0; h < 16; ++h)
                    w += Wpost_s[a*16 + h] * Ps[h*SS_HS + ii*SS_IS + jj];
                const uint32_t* vp = vbase + jj * 32;
                #pragma unroll
                for (int dd = 0; dd < 32; ++dd) {
                    uint32_t u = vp[dd];
                    O[2*dd+0] += w * bflo(u);
                    O[2*dd+1] += w * bfhi(u);
                }
            }
        }
    }

    // write output row (b, a, i, :)
    {
        float* op = out + (((size_t)b*H_ + a)*N_ + i)*D_;
        #pragma unroll
        for (int x = 0; x < 16; ++x) {
            float4 f;
            f.x = O[4*x+0]; f.y = O[4*x+1]; f.z = O[4*x+2]; f.w = O[4*x+3];
            *(float4*)(op + 4*x) = f;
        }
    }
}

extern "C" void kernel_launch(void* const* d_in, const int* in_sizes, int n_in,
                              void* d_out, int out_size, void* d_ws, size_t ws_size,
                              hipStream_t stream) {
    const float* q     = (const float*)d_in[0];
    const float* k     = (const float*)d_in[1];
    const float* v     = (const float*)d_in[2];
    const float* Wpre  = (const float*)d_in[3];
    const float* Wpost = (const float*)d_in[4];
    float* out = (float*)d_out;

    dim3 grid(B_ * (N_ / IB));  // 256 workgroups
    dim3 block(256);
    attend_th_kernel<<<grid, block, 0, stream>>>(q, k, v, Wpre, Wpost, out);
}

// Round 2
// 423.241 us; speedup vs baseline: 4.9428x; 4.9428x over previous
//
#include <hip/hip_runtime.h>
#include <stdint.h>

#define B_  4
#define H_  16
#define N_  1024
#define D_  64

typedef _Float16 half4v __attribute__((ext_vector_type(4)));
typedef _Float16 half2v __attribute__((ext_vector_type(2)));
typedef float    f32x4  __attribute__((ext_vector_type(4)));

#define KS_RS 68   // halfs per K-row (64 + 4 pad) -> 136B, 8B aligned frags
#define SS_RS 20   // floats per S/P row (16 + 4 pad) -> 80B, 16B aligned
#define AS_RS 20   // halfs per A row (16 + 4 pad) -> 40B, 8B aligned frags
#define VT_RS 24   // halfs per VsT row (16 + 8 pad) -> 48B, 8B aligned frags

// per-batch WG id [0,160) -> (i-tile, chunk). chunks(it)=ceil((it+1)/16)
__device__ __forceinline__ void decode_wg(int wid, int& it, int& c) {
    if (wid < 16)      { it = wid;                     c = 0;     }
    else if (wid < 48) { int u = wid - 16; it = 16 + (u >> 1); c = u & 1; }
    else if (wid < 96) { int u = wid - 48; it = 32 + u / 3;    c = u % 3; }
    else               { int u = wid - 96; it = 48 + (u >> 2); c = u & 3; }
}

// ---------------- Kernel A: softmax denominators l[b,h,i] ----------------
__global__ __launch_bounds__(256, 2)
void attend_lsum(const float* __restrict__ q, const float* __restrict__ k,
                 const float* __restrict__ Wpre, float* __restrict__ lbuf) {
    __shared__ _Float16 Ks[H_ * 16 * KS_RS];   // 34,816 B
    __shared__ float    Ss[H_ * 16 * SS_RS];   // 20,480 B
    __shared__ float    WpreS[256];

    const int t = threadIdx.x;
    const int b = blockIdx.x / 160;
    int it, c; decode_wg(blockIdx.x % 160, it, c);
    const int i0 = it * 16;
    const int jt0 = c * 16;
    const int jt1 = min(c * 16 + 16, it + 1);

    WpreS[t] = Wpre[t];

    const int lane = t & 63, w = t >> 6;
    const int l16 = lane & 15, lg = lane >> 4;
    const int g = t >> 4, ii = t & 15;

    // Q fragments for this wave's 4 heads (scale folded in)
    half4v qf[4][4];
    #pragma unroll
    for (int hh = 0; hh < 4; ++hh) {
        const int h = w * 4 + hh;
        const float* qrow = q + (((size_t)b * H_ + h) * N_ + i0 + l16) * D_;
        #pragma unroll
        for (int kk = 0; kk < 4; ++kk) {
            f32x4 qv = *(const f32x4*)(qrow + kk * 16 + lg * 4);
            half4v hv;
            #pragma unroll
            for (int e = 0; e < 4; ++e) hv[e] = (_Float16)(qv[e] * 0.125f);
            qf[hh][kk] = hv;
        }
    }

    float lacc = 0.0f;

    for (int jt = jt0; jt < jt1; ++jt) {
        const int j0 = jt * 16;
        __syncthreads();
        // stage K tile: 16 heads x 16 rows x 64, f32 -> f16
        {
            const int j = t >> 4, dq = t & 15;
            #pragma unroll
            for (int h = 0; h < 16; ++h) {
                f32x4 kv = *(const f32x4*)(k + (((size_t)b * H_ + h) * N_ + j0 + j) * D_ + dq * 4);
                half4v hv;
                #pragma unroll
                for (int e = 0; e < 4; ++e) hv[e] = (_Float16)kv[e];
                *(half4v*)&Ks[(h * 16 + j) * KS_RS + dq * 4] = hv;
            }
        }
        __syncthreads();
        // QK^T via MFMA, write S to LDS
        #pragma unroll
        for (int hh = 0; hh < 4; ++hh) {
            const int h = w * 4 + hh;
            f32x4 acc = {0.f, 0.f, 0.f, 0.f};
            #pragma unroll
            for (int kk = 0; kk < 4; ++kk) {
                half4v bf = *(const half4v*)&Ks[(h * 16 + l16) * KS_RS + kk * 16 + lg * 4];
                acc = __builtin_amdgcn_mfma_f32_16x16x16f16(qf[hh][kk], bf, acc, 0, 0, 0);
            }
            #pragma unroll
            for (int r = 0; r < 4; ++r)
                Ss[(h * 16 + lg * 4 + r) * SS_RS + l16] = acc[r];
        }
        __syncthreads();
        // pre-softmax talking-heads mix + exp row-sum (thread (g, ii))
        {
            float M[16];
            #pragma unroll
            for (int j = 0; j < 16; ++j) M[j] = 0.f;
            #pragma unroll
            for (int h = 0; h < 16; ++h) {
                const float wg = WpreS[g * 16 + h];
                const f32x4* sp = (const f32x4*)&Ss[(h * 16 + ii) * SS_RS];
                #pragma unroll
                for (int jq = 0; jq < 4; ++jq) {
                    f32x4 s = sp[jq];
                    #pragma unroll
                    for (int e = 0; e < 4; ++e) M[jq * 4 + e] += wg * s[e];
                }
            }
            const int jmax = (jt == it) ? ii : 15;
            #pragma unroll
            for (int j = 0; j < 16; ++j)
                if (j <= jmax) lacc += __expf(M[j]);
        }
    }

    atomicAdd(&lbuf[((size_t)b * H_ + g) * N_ + i0 + ii], lacc);
}

// ---------------- Kernel B: output ----------------
__global__ __launch_bounds__(256, 1)
void attend_out(const float* __restrict__ q, const float* __restrict__ k,
                const float* __restrict__ v, const float* __restrict__ Wpre,
                const float* __restrict__ Wpost, const float* __restrict__ lbuf,
                float* __restrict__ out) {
    __shared__ _Float16 Ks[H_ * 16 * KS_RS];    // 34,816 B
    __shared__ _Float16 VsT[H_ * 64 * VT_RS];   // 49,152 B  (V transposed: [h][d][j])
    __shared__ float    Ss[H_ * 16 * SS_RS];    // 20,480 B
    __shared__ float    Ps[H_ * 16 * SS_RS];    // 20,480 B
    __shared__ _Float16 As[H_ * 16 * AS_RS];    // 12,800 B
    __shared__ float    WpreS[256], WpostS[256];

    const int t = threadIdx.x;
    const int b = blockIdx.x / 160;
    int it, c; decode_wg(blockIdx.x % 160, it, c);
    const int i0 = it * 16;
    const int jt0 = c * 16;
    const int jt1 = min(c * 16 + 16, it + 1);

    WpreS[t]  = Wpre[t];
    WpostS[t] = Wpost[t];

    const int lane = t & 63, w = t >> 6;
    const int l16 = lane & 15, lg = lane >> 4;
    const int g = t >> 4, ii = t & 15;

    // Q fragments (scale folded)
    half4v qf[4][4];
    #pragma unroll
    for (int hh = 0; hh < 4; ++hh) {
        const int h = w * 4 + hh;
        const float* qrow = q + (((size_t)b * H_ + h) * N_ + i0 + l16) * D_;
        #pragma unroll
        for (int kk = 0; kk < 4; ++kk) {
            f32x4 qv = *(const f32x4*)(qrow + kk * 16 + lg * 4);
            half4v hv;
            #pragma unroll
            for (int e = 0; e < 4; ++e) hv[e] = (_Float16)(qv[e] * 0.125f);
            qf[hh][kk] = hv;
        }
    }

    const float lrecip = 1.0f / lbuf[((size_t)b * H_ + g) * N_ + i0 + ii];

    f32x4 oacc[4][4];
    #pragma unroll
    for (int hh = 0; hh < 4; ++hh)
        #pragma unroll
        for (int ds = 0; ds < 4; ++ds)
            oacc[hh][ds] = (f32x4){0.f, 0.f, 0.f, 0.f};

    for (int jt = jt0; jt < jt1; ++jt) {
        const int j0 = jt * 16;
        __syncthreads();
        // stage K
        {
            const int j = t >> 4, dq = t & 15;
            #pragma unroll
            for (int h = 0; h < 16; ++h) {
                f32x4 kv = *(const f32x4*)(k + (((size_t)b * H_ + h) * N_ + j0 + j) * D_ + dq * 4);
                half4v hv;
                #pragma unroll
                for (int e = 0; e < 4; ++e) hv[e] = (_Float16)kv[e];
                *(half4v*)&Ks[(h * 16 + j) * KS_RS + dq * 4] = hv;
            }
        }
        // stage V transposed: VsT[h][d][j]
        #pragma unroll
        for (int rep = 0; rep < 8; ++rep) {
            const int task = rep * 256 + t;
            const int h = task >> 7, rem = task & 127;
            const int jp = rem & 7, dblk = rem >> 3;
            const float* vb0 = v + (((size_t)b * H_ + h) * N_ + j0 + 2 * jp) * D_ + dblk * 4;
            f32x4 va = *(const f32x4*)(vb0);
            f32x4 vb = *(const f32x4*)(vb0 + D_);
            #pragma unroll
            for (int e = 0; e < 4; ++e) {
                half2v hv;
                hv[0] = (_Float16)va[e];
                hv[1] = (_Float16)vb[e];
                *(half2v*)&VsT[(h * 64 + dblk * 4 + e) * VT_RS + 2 * jp] = hv;
            }
        }
        __syncthreads();
        // QK^T
        #pragma unroll
        for (int hh = 0; hh < 4; ++hh) {
            const int h = w * 4 + hh;
            f32x4 acc = {0.f, 0.f, 0.f, 0.f};
            #pragma unroll
            for (int kk = 0; kk < 4; ++kk) {
                half4v bf = *(const half4v*)&Ks[(h * 16 + l16) * KS_RS + kk * 16 + lg * 4];
                acc = __builtin_amdgcn_mfma_f32_16x16x16f16(qf[hh][kk], bf, acc, 0, 0, 0);
            }
            #pragma unroll
            for (int r = 0; r < 4; ++r)
                Ss[(h * 16 + lg * 4 + r) * SS_RS + l16] = acc[r];
        }
        __syncthreads();
        // pre-mix + exp + normalize -> Ps  (thread role: softmax head g)
        {
            float M[16];
            #pragma unroll
            for (int j = 0; j < 16; ++j) M[j] = 0.f;
            #pragma unroll
            for (int h = 0; h < 16; ++h) {
                const float wg = WpreS[g * 16 + h];
                const f32x4* sp = (const f32x4*)&Ss[(h * 16 + ii) * SS_RS];
                #pragma unroll
                for (int jq = 0; jq < 4; ++jq) {
                    f32x4 s = sp[jq];
                    #pragma unroll
                    for (int e = 0; e < 4; ++e) M[jq * 4 + e] += wg * s[e];
                }
            }
            const int jmax = (jt == it) ? ii : 15;
            #pragma unroll
            for (int jq = 0; jq < 4; ++jq) {
                f32x4 pw;
                #pragma unroll
                for (int e = 0; e < 4; ++e) {
                    const int j = jq * 4 + e;
                    pw[e] = (j <= jmax) ? __expf(M[j]) * lrecip : 0.f;
                }
                *(f32x4*)&Ps[(g * 16 + ii) * SS_RS + jq * 4] = pw;
            }
        }
        __syncthreads();
        // post-mix -> As (f16)   (thread role: output head g)
        {
            float A[16];
            #pragma unroll
            for (int j = 0; j < 16; ++j) A[j] = 0.f;
            #pragma unroll
            for (int h = 0; h < 16; ++h) {
                const float wg = WpostS[g * 16 + h];
                const f32x4* pp = (const f32x4*)&Ps[(h * 16 + ii) * SS_RS];
                #pragma unroll
                for (int jq = 0; jq < 4; ++jq) {
                    f32x4 s = pp[jq];
                    #pragma unroll
                    for (int e = 0; e < 4; ++e) A[jq * 4 + e] += wg * s[e];
                }
            }
            #pragma unroll
            for (int jq = 0; jq < 4; ++jq) {
                half4v hv;
                #pragma unroll
                for (int e = 0; e < 4; ++e) hv[e] = (_Float16)A[jq * 4 + e];
                *(half4v*)&As[(g * 16 + ii) * AS_RS + jq * 4] = hv;
            }
        }
        __syncthreads();
        // PV via MFMA: O[g] += A[g] x V[g]
        #pragma unroll
        for (int hh = 0; hh < 4; ++hh) {
            const int h = w * 4 + hh;
            half4v afr = *(const half4v*)&As[(h * 16 + l16) * AS_RS + lg * 4];
            #pragma unroll
            for (int ds = 0; ds < 4; ++ds) {
                half4v vfr = *(const half4v*)&VsT[(h * 64 + ds * 16 + l16) * VT_RS + lg * 4];
                oacc[hh][ds] = __builtin_amdgcn_mfma_f32_16x16x16f16(afr, vfr, oacc[hh][ds], 0, 0, 0);
            }
        }
    }

    // accumulate output (chunks of same row-tile add disjoint j-ranges)
    #pragma unroll
    for (int hh = 0; hh < 4; ++hh) {
        const int h = w * 4 + hh;
        #pragma unroll
        for (int ds = 0; ds < 4; ++ds) {
            #pragma unroll
            for (int r = 0; r < 4; ++r) {
                const size_t idx = (((size_t)b * H_ + h) * N_ + i0 + lg * 4 + r) * D_ + ds * 16 + l16;
                atomicAdd(&out[idx], oacc[hh][ds][r]);
            }
        }
    }
}

extern "C" void kernel_launch(void* const* d_in, const int* in_sizes, int n_in,
                              void* d_out, int out_size, void* d_ws, size_t ws_size,
                              hipStream_t stream) {
    const float* q     = (const float*)d_in[0];
    const float* k     = (const float*)d_in[1];
    const float* v     = (const float*)d_in[2];
    const float* Wpre  = (const float*)d_in[3];
    const float* Wpost = (const float*)d_in[4];
    float* out  = (float*)d_out;
    float* lbuf = (float*)d_ws;

    hipMemsetAsync(d_out, 0, (size_t)out_size * sizeof(float), stream);
    hipMemsetAsync(d_ws, 0, (size_t)B_ * H_ * N_ * sizeof(float), stream);

    dim3 grid(B_ * 160);   // 640 balanced chunks
    dim3 block(256);
    attend_lsum<<<grid, block, 0, stream>>>(q, k, Wpre, lbuf);
    attend_out<<<grid, block, 0, stream>>>(q, k, v, Wpre, Wpost, lbuf, out);
}

// Round 3
// 319.741 us; speedup vs baseline: 6.5427x; 1.3237x over previous
//
#include <hip/hip_runtime.h>
#include <stdint.h>

#define B_  4
#define H_  16
#define N_  1024
#define D_  64
#define SS_II 328   // halfs per ii-row of Ss:  [ii][jj*20 + h], +8 pad
#define A2_G  328   // halfs per g-row of A2s:  [g][ii*20 + jj], +8 pad

typedef _Float16 half4v __attribute__((ext_vector_type(4)));
typedef float    f32x4  __attribute__((ext_vector_type(4)));

__device__ __forceinline__ half4v cvt4(f32x4 v) {
    half4v h;
    h[0] = (_Float16)v[0]; h[1] = (_Float16)v[1];
    h[2] = (_Float16)v[2]; h[3] = (_Float16)v[3];
    return h;
}

// per-batch WG id [0,160) -> (i-tile, chunk). chunks(it)=ceil((it+1)/16)
__device__ __forceinline__ void decode_wg(int wid, int& it, int& c) {
    if (wid < 16)      { it = wid;                     c = 0;     }
    else if (wid < 48) { int u = wid - 16; it = 16 + (u >> 1); c = u & 1; }
    else if (wid < 96) { int u = wid - 48; it = 32 + u / 3;    c = u % 3; }
    else               { int u = wid - 96; it = 48 + (u >> 2); c = u & 3; }
}

// ---------------- Kernel A: softmax denominators l[b,h,i] ----------------
__global__ __launch_bounds__(256, 3)
void attend_lsum(const float* __restrict__ q, const float* __restrict__ k,
                 const float* __restrict__ Wpre, float* __restrict__ lbuf) {
    __shared__ _Float16 Ss[16 * SS_II];   // 10,496 B

    const int t = threadIdx.x;
    const int b = blockIdx.x / 160;
    int it, c; decode_wg(blockIdx.x % 160, it, c);
    const int i0 = it * 16;
    const int jt0 = c * 16;
    const int jt1 = min(c * 16 + 16, it + 1);

    const int lane = t & 63, w = t >> 6;
    const int l16 = lane & 15, lg = lane >> 4;

    // Wpre A-fragment: A[g=l16, h=4lg+e]
    const half4v wpre_f = cvt4(*(const f32x4*)(Wpre + l16 * 16 + 4 * lg));

    // Q fragments for wave's 4 heads (scale folded)
    half4v qf[4][4];
    #pragma unroll
    for (int hh = 0; hh < 4; ++hh) {
        const int h = w * 4 + hh;
        const float* qrow = q + (((size_t)b * H_ + h) * N_ + i0 + l16) * D_;
        #pragma unroll
        for (int kk = 0; kk < 4; ++kk) {
            f32x4 qv = *(const f32x4*)(qrow + kk * 16 + 4 * lg);
            half4v hv;
            #pragma unroll
            for (int e = 0; e < 4; ++e) hv[e] = (_Float16)(qv[e] * 0.125f);
            qf[hh][kk] = hv;
        }
    }

    float lp[4][4];
    #pragma unroll
    for (int ss = 0; ss < 4; ++ss)
        #pragma unroll
        for (int r = 0; r < 4; ++r) lp[ss][r] = 0.f;

    for (int jt = jt0; jt < jt1; ++jt) {
        const int j0 = jt * 16;
        // QK^T (K direct from global) + S write
        #pragma unroll
        for (int hh = 0; hh < 4; ++hh) {
            const int h = w * 4 + hh;
            const float* krow = k + (((size_t)b * H_ + h) * N_ + j0 + l16) * D_ + 4 * lg;
            f32x4 acc = {0.f, 0.f, 0.f, 0.f};
            #pragma unroll
            for (int kk = 0; kk < 4; ++kk) {
                f32x4 kv = *(const f32x4*)(krow + kk * 16);
                acc = __builtin_amdgcn_mfma_f32_16x16x16f16(qf[hh][kk], cvt4(kv), acc, 0, 0, 0);
            }
            #pragma unroll
            for (int r = 0; r < 4; ++r)
                Ss[(4 * lg + r) * SS_II + l16 * 20 + h] = (_Float16)acc[r];
        }
        __syncthreads();
        // mix1 via MFMA + masked exp accumulate (wave's 4 ii-slices)
        #pragma unroll
        for (int ss = 0; ss < 4; ++ss) {
            const int sii = 4 * w + ss;
            half4v sfrag = *(const half4v*)&Ss[sii * SS_II + l16 * 20 + 4 * lg];
            f32x4 z = {0.f, 0.f, 0.f, 0.f};
            f32x4 m1 = __builtin_amdgcn_mfma_f32_16x16x16f16(wpre_f, sfrag, z, 0, 0, 0);
            const bool ok = (jt < it) || (l16 <= sii);
            if (ok) {
                #pragma unroll
                for (int r = 0; r < 4; ++r) lp[ss][r] += __expf(m1[r]);
            }
        }
        __syncthreads();
    }

    // reduce over jj (= l16 groups) and atomically add
    #pragma unroll
    for (int ss = 0; ss < 4; ++ss) {
        #pragma unroll
        for (int r = 0; r < 4; ++r) {
            float v = lp[ss][r];
            v += __shfl_xor(v, 1, 64);
            v += __shfl_xor(v, 2, 64);
            v += __shfl_xor(v, 4, 64);
            v += __shfl_xor(v, 8, 64);
            if (l16 == 0)
                atomicAdd(&lbuf[((size_t)b * H_ + 4 * lg + r) * N_ + i0 + 4 * w + ss], v);
        }
    }
}

// ---------------- Kernel B: output ----------------
__global__ __launch_bounds__(256, 2)
void attend_out(const float* __restrict__ q, const float* __restrict__ k,
                const float* __restrict__ v, const float* __restrict__ Wpre,
                const float* __restrict__ Wpost, const float* __restrict__ lbuf,
                float* __restrict__ out) {
    __shared__ _Float16 Ss[16 * SS_II];    // 10,496 B
    __shared__ _Float16 A2s[16 * A2_G];    // 10,496 B

    const int t = threadIdx.x;
    const int b = blockIdx.x / 160;
    int it, c; decode_wg(blockIdx.x % 160, it, c);
    const int i0 = it * 16;
    const int jt0 = c * 16;
    const int jt1 = min(c * 16 + 16, it + 1);

    const int lane = t & 63, w = t >> 6;
    const int l16 = lane & 15, lg = lane >> 4;

    const half4v wpre_f  = cvt4(*(const f32x4*)(Wpre  + l16 * 16 + 4 * lg));
    const half4v wpost_f = cvt4(*(const f32x4*)(Wpost + l16 * 16 + 4 * lg));

    // Q fragments (scale folded)
    half4v qf[4][4];
    #pragma unroll
    for (int hh = 0; hh < 4; ++hh) {
        const int h = w * 4 + hh;
        const float* qrow = q + (((size_t)b * H_ + h) * N_ + i0 + l16) * D_;
        #pragma unroll
        for (int kk = 0; kk < 4; ++kk) {
            f32x4 qv = *(const f32x4*)(qrow + kk * 16 + 4 * lg);
            half4v hv;
            #pragma unroll
            for (int e = 0; e < 4; ++e) hv[e] = (_Float16)(qv[e] * 0.125f);
            qf[hh][kk] = hv;
        }
    }

    // 1/l for softmax head h=4lg+r, row ii=4w+ss
    float lrecip[4][4];
    #pragma unroll
    for (int ss = 0; ss < 4; ++ss)
        #pragma unroll
        for (int r = 0; r < 4; ++r)
            lrecip[ss][r] = 1.0f / lbuf[((size_t)b * H_ + 4 * lg + r) * N_ + i0 + 4 * w + ss];

    f32x4 oacc[4][4];
    #pragma unroll
    for (int hh = 0; hh < 4; ++hh)
        #pragma unroll
        for (int ds = 0; ds < 4; ++ds)
            oacc[hh][ds] = (f32x4){0.f, 0.f, 0.f, 0.f};

    for (int jt = jt0; jt < jt1; ++jt) {
        const int j0 = jt * 16;
        // QK^T (K direct from global) + S write
        #pragma unroll
        for (int hh = 0; hh < 4; ++hh) {
            const int h = w * 4 + hh;
            const float* krow = k + (((size_t)b * H_ + h) * N_ + j0 + l16) * D_ + 4 * lg;
            f32x4 acc = {0.f, 0.f, 0.f, 0.f};
            #pragma unroll
            for (int kk = 0; kk < 4; ++kk) {
                f32x4 kv = *(const f32x4*)(krow + kk * 16);
                acc = __builtin_amdgcn_mfma_f32_16x16x16f16(qf[hh][kk], cvt4(kv), acc, 0, 0, 0);
            }
            #pragma unroll
            for (int r = 0; r < 4; ++r)
                Ss[(4 * lg + r) * SS_II + l16 * 20 + h] = (_Float16)acc[r];
        }
        __syncthreads();
        // mix1 -> exp/mask/normalize (in-register) -> mix2 -> A2 write
        #pragma unroll
        for (int ss = 0; ss < 4; ++ss) {
            const int sii = 4 * w + ss;
            half4v sfrag = *(const half4v*)&Ss[sii * SS_II + l16 * 20 + 4 * lg];
            f32x4 z = {0.f, 0.f, 0.f, 0.f};
            f32x4 m1 = __builtin_amdgcn_mfma_f32_16x16x16f16(wpre_f, sfrag, z, 0, 0, 0);
            const bool ok = (jt < it) || (l16 <= sii);
            half4v pfrag;
            #pragma unroll
            for (int r = 0; r < 4; ++r)
                pfrag[r] = (_Float16)(ok ? __expf(m1[r]) * lrecip[ss][r] : 0.f);
            f32x4 m2 = __builtin_amdgcn_mfma_f32_16x16x16f16(wpost_f, pfrag, z, 0, 0, 0);
            #pragma unroll
            for (int r = 0; r < 4; ++r)
                A2s[(4 * lg + r) * A2_G + sii * 20 + l16] = (_Float16)m2[r];
        }
        __syncthreads();
        // PV: O^T[d,i] += V^T[d,j] * A2^T[j,i]   (V direct from global)
        #pragma unroll
        for (int hh = 0; hh < 4; ++hh) {
            const int h = w * 4 + hh;
            half4v bfrag = *(const half4v*)&A2s[h * A2_G + l16 * 20 + 4 * lg];
            const float* vbase = v + (((size_t)b * H_ + h) * N_ + j0) * D_ + l16;
            #pragma unroll
            for (int ds = 0; ds < 4; ++ds) {
                f32x4 vv;
                #pragma unroll
                for (int e = 0; e < 4; ++e)
                    vv[e] = vbase[(size_t)(4 * lg + e) * D_ + ds * 16];
                oacc[hh][ds] = __builtin_amdgcn_mfma_f32_16x16x16f16(cvt4(vv), bfrag, oacc[hh][ds], 0, 0, 0);
            }
        }
    }

    // accumulate output: O[i0+l16, ds*16+4lg+r] for wave's heads
    #pragma unroll
    for (int hh = 0; hh < 4; ++hh) {
        const int h = w * 4 + hh;
        float* orow = out + (((size_t)b * H_ + h) * N_ + i0 + l16) * D_;
        #pragma unroll
        for (int ds = 0; ds < 4; ++ds) {
            #pragma unroll
            for (int r = 0; r < 4; ++r)
                atomicAdd(&orow[ds * 16 + 4 * lg + r], oacc[hh][ds][r]);
        }
    }
}

extern "C" void kernel_launch(void* const* d_in, const int* in_sizes, int n_in,
                              void* d_out, int out_size, void* d_ws, size_t ws_size,
                              hipStream_t stream) {
    const float* q     = (const float*)d_in[0];
    const float* k     = (const float*)d_in[1];
    const float* v     = (const float*)d_in[2];
    const float* Wpre  = (const float*)d_in[3];
    const float* Wpost = (const float*)d_in[4];
    float* out  = (float*)d_out;
    float* lbuf = (float*)d_ws;

    hipMemsetAsync(d_out, 0, (size_t)out_size * sizeof(float), stream);
    hipMemsetAsync(d_ws, 0, (size_t)B_ * H_ * N_ * sizeof(float), stream);

    dim3 grid(B_ * 160);   // 640 balanced chunks
    dim3 block(256);
    attend_lsum<<<grid, block, 0, stream>>>(q, k, Wpre, lbuf);
    attend_out<<<grid, block, 0, stream>>>(q, k, v, Wpre, Wpost, lbuf, out);
}